// Round 12
// baseline (719.564 us; speedup 1.0000x reference)
//
#include <hip/hip_runtime.h>
#include <cstdint>

#define B_ 64
#define N_ 512
#define D_ 256
#define L_ 4

typedef __bf16 bf16;
typedef __attribute__((ext_vector_type(8))) __bf16 bf16x8;
typedef __attribute__((ext_vector_type(4))) __bf16 bf16x4;
typedef __attribute__((ext_vector_type(4))) float f32x4;

#define MFMA16(a, b, c) __builtin_amdgcn_mfma_f32_16x16x32_bf16((a), (b), (c), 0, 0, 0)

__device__ __forceinline__ float sigmoidf_(float z) {
  return 1.0f / (1.0f + __expf(-z));
}

// ===========================================================================
// R12 = R11 + prefetch depth extended to the 256-VGPR budget:
//  - p1 B-stream prefetch 4->6 of 8 ks (24 loads, 96 VGPR)
//  - p3 B-stream prefetch 8->12 of 16 ks, issued BEFORE p1's sigmoid
//    epilogue (~1800cy VALU) for longer flight under guaranteed compute
//  - pack_w x4 + init_pack merged into one `prep` kernel (5 launches -> 1)
// Occupancy-overlap alternative refuted by R6-vs-R8 (packed regime);
// 2-block redesign infeasible (128-VGPR cap < acc+prefetch).
// ===========================================================================

// lgkmcnt-only barrier: LDS ordering w/o vmcnt drain. sched_barrier pins
// (rule #18: MFMA can be hoisted past inline-asm waits otherwise).
#define BARSYNC() do { \
    asm volatile("s_waitcnt lgkmcnt(0)\n\ts_barrier" ::: "memory"); \
    __builtin_amdgcn_sched_barrier(0); \
  } while (0)

#define UIDX(u) (((size_t)(u)) * 64 + lane)

// ---------------------------------------------------------------------------
// prep: packs 13 weight matrices (f32->bf16 fragments) AND x -> xbpk/xTpk,
// one launch. bid<416: weights (13x128 units); else: init units.
// ---------------------------------------------------------------------------
__global__ __launch_bounds__(256) void prep(
    const float* __restrict__ x,
    const float* __restrict__ wattn, const float* __restrict__ w0,
    const float* __restrict__ w1, const float* __restrict__ wf,
    bf16* __restrict__ wb, bf16* __restrict__ xbpk, bf16* __restrict__ xTpk)
{
  const int tid = threadIdx.x, lane = tid & 63;
  const int bid = blockIdx.x;
  if (bid < 416) {            // 13 matrices x 128 units, 4 units/block
    const int U = bid * 4 + (tid >> 6);
    const int m = U >> 7, u = U & 127;
    const float* src = (m < 4)  ? wattn + (size_t)m * (D_ * D_)
                     : (m < 8)  ? w0 + (size_t)(m - 4) * (D_ * D_)
                     : (m < 12) ? w1 + (size_t)(m - 8) * (D_ * D_)
                                : wf;
    const int r16 = u >> 3, kc = u & 7;
    const int row = r16 * 16 + (lane & 15);
    const int k0 = kc * 32 + (lane >> 4) * 8;
    const float* s = src + (size_t)row * D_ + k0;
    const float4 v0 = *(const float4*)s;
    const float4 v1 = *(const float4*)(s + 4);
    bf16x8 o;
    o[0] = (bf16)v0.x; o[1] = (bf16)v0.y; o[2] = (bf16)v0.z; o[3] = (bf16)v0.w;
    o[4] = (bf16)v1.x; o[5] = (bf16)v1.y; o[6] = (bf16)v1.z; o[7] = (bf16)v1.w;
    ((bf16x8*)wb)[(size_t)U * 64 + lane] = o;
    return;
  }
  const int U = (bid - 416) * 4 + (tid >> 6);   // 0..32767
  const int b = U >> 9, u = U & 511;
  if (u < 256) {            // xbpk unit: r16 = n/16, kc = d/32
    const int n = (u >> 3) * 16 + (lane & 15);
    const int d = (u & 7) * 32 + (lane >> 4) * 8;
    const float* s = x + ((size_t)(b * N_ + n)) * D_ + d;
    const float4 v0 = *(const float4*)s;
    const float4 v1 = *(const float4*)(s + 4);
    bf16x8 o;
    o[0] = (bf16)v0.x; o[1] = (bf16)v0.y; o[2] = (bf16)v0.z; o[3] = (bf16)v0.w;
    o[4] = (bf16)v1.x; o[5] = (bf16)v1.y; o[6] = (bf16)v1.z; o[7] = (bf16)v1.w;
    ((bf16x8*)xbpk)[((size_t)b * 256 + u) * 64 + lane] = o;
  } else {                  // xTpk unit: r16 = d/16, kc = n/32
    const int u2 = u - 256;
    const int d = (u2 >> 4) * 16 + (lane & 15);
    const int n = (u2 & 15) * 32 + (lane >> 4) * 8;
    bf16x8 o;
#pragma unroll
    for (int e = 0; e < 8; ++e)
      o[e] = (bf16)x[((size_t)(b * N_ + n + e)) * D_ + d];
    ((bf16x8*)xTpk)[((size_t)b * 256 + u2) * 64 + lane] = o;
  }
}

// ---------------------------------------------------------------------------
// gat_layer: one block per (64-row strip, batch); 512 threads (8 waves);
// LDS ~104 KB -> 1 block/CU. Grid 512. lgkm-only barriers + deep prefetch.
// ---------------------------------------------------------------------------
__global__ __launch_bounds__(512, 1) void gat_layer(
    const bf16* __restrict__ xbpk_in, const bf16* __restrict__ xTpk_in,
    bf16* __restrict__ xbpk_out, bf16* __restrict__ xTpk_out,
    const bf16* __restrict__ Wap, const float* __restrict__ ba,
    const bf16* __restrict__ W0p, const float* __restrict__ b0,
    const bf16* __restrict__ W1p, const float* __restrict__ b1,
    const float* __restrict__ adj, const unsigned short* __restrict__ bits_in,
    unsigned short* __restrict__ bits_out, float* __restrict__ outA)
{
  __shared__ bf16 qs[64 * 264];     // q / x' / out-stage (stride 264)  33.8KB
  __shared__ bf16 xps[64 * 520];    // P (stride 520) / h (stride 264)  66.6KB
  __shared__ float psum[8][64];     //                                   2KB
  __shared__ float rinvs[64];
  __shared__ unsigned int bits_s[1024];  // 64 rows x 32 uint16          4KB

  const int tid = threadIdx.x, w = tid >> 6, lane = tid & 63;
  const int l16 = lane & 15, quad = lane >> 4;
  const int wg = blockIdx.x;
  const int lid = (wg & 7) * 64 + (wg >> 3);   // bijective XCD swizzle
  const int b = lid >> 3;                      // 8 strips per batch
  const int row0 = (lid & 7) * 64;

  const bf16x8* Xbp = (const bf16x8*)xbpk_in + (size_t)b * 16384;
  const bf16x8* Xtp = (const bf16x8*)xTpk_in + (size_t)b * 16384;
  bf16x8* XbpO = (bf16x8*)xbpk_out + (size_t)b * 16384;
  bf16x8* XtpO = (bf16x8*)xTpk_out + (size_t)b * 16384;
  const bf16x8* Wa8 = (const bf16x8*)Wap;
  const bf16x8* W08 = (const bf16x8*)W0p;
  const bf16x8* W18 = (const bf16x8*)W1p;

  if (bits_in) {
#pragma unroll
    for (int e = 0; e < 2; ++e) {
      const int t = tid + e * 512;
      bits_s[t] = ((const unsigned int*)bits_in)[((size_t)b * N_ + row0) * 16 + t];
    }
  }

  // ---- p0: q = x @ Wa^T + ba ; A straight from packed global (dense) ----
  bf16x8 bxp[6][4];   // p1 B-stream prefetch, ks 0..5 (96 VGPR)
  {
    f32x4 acc0[4][2] = {};
#pragma unroll
    for (int ks = 0; ks < 8; ++ks) {
      bf16x8 af[4];
#pragma unroll
      for (int m = 0; m < 4; ++m)
        af[m] = Xbp[UIDX(((row0 >> 4) + m) * 8 + ks)];
      bf16x8 bw[2];
#pragma unroll
      for (int i = 0; i < 2; ++i)
        bw[i] = Wa8[UIDX((2 * w + i) * 8 + ks)];
#pragma unroll
      for (int m = 0; m < 4; ++m)
#pragma unroll
        for (int i = 0; i < 2; ++i) acc0[m][i] = MFMA16(af[m], bw[i], acc0[m][i]);
    }
    // T14-deep: p1's B-stream ks 0..5 issues here, crosses b1 in flight
#pragma unroll
    for (int ks = 0; ks < 6; ++ks)
#pragma unroll
      for (int jt = 0; jt < 4; ++jt)
        bxp[ks][jt] = Xbp[UIDX((4 * w + jt) * 8 + ks)];
    __builtin_amdgcn_sched_barrier(0);
#pragma unroll
    for (int m = 0; m < 4; ++m)
#pragma unroll
      for (int i = 0; i < 2; ++i) {
        const int col = 32 * w + 16 * i + l16;
        const float bv = ba[col];
#pragma unroll
        for (int r = 0; r < 4; ++r)
          qs[(16 * m + quad * 4 + r) * 264 + col] = (bf16)(acc0[m][i][r] + bv);
      }
  }
  BARSYNC();   // b1: qs(q) + bits_s ready (LDS only; bxp stays in flight)

  // ---- p1: P = sigmoid(q @ x^T) masked -> xps ----
  float p[4][4] = {};
  bf16x8 btp[12][2];   // p3 B-stream prefetch, ks 0..11 (96 VGPR)
  {
    f32x4 acc1[4][4] = {};
#pragma unroll
    for (int ks = 0; ks < 8; ++ks) {
      bf16x8 af[4];
#pragma unroll
      for (int m = 0; m < 4; ++m)
        af[m] = *(const bf16x8*)&qs[(16 * m + l16) * 264 + ks * 32 + quad * 8];
      bf16x8 bx[4];
#pragma unroll
      for (int jt = 0; jt < 4; ++jt)
        bx[jt] = (ks < 6) ? bxp[ks][jt] : Xbp[UIDX((4 * w + jt) * 8 + ks)];
#pragma unroll
      for (int m = 0; m < 4; ++m)
#pragma unroll
        for (int jt = 0; jt < 4; ++jt)
          acc1[m][jt] = MFMA16(af[m], bx[jt], acc1[m][jt]);
    }
    // T14-deep: p3's B-stream ks 0..11 issues here, BEFORE the sigmoid
    // epilogue (~1800cy VALU) - crosses b2/b3/p2 under guaranteed compute.
#pragma unroll
    for (int ks = 0; ks < 12; ++ks)
#pragma unroll
      for (int i = 0; i < 2; ++i)
        btp[ks][i] = Xtp[UIDX((2 * w + i) * 16 + ks)];
    __builtin_amdgcn_sched_barrier(0);

#pragma unroll
    for (int jt = 0; jt < 4; ++jt) {
      const int lcol = 64 * w + jt * 16 + l16;
      const int piece = 4 * w + jt;
#pragma unroll
      for (int m = 0; m < 4; ++m)
#pragma unroll
        for (int r = 0; r < 4; ++r) {
          const int row = 16 * m + quad * 4 + r;
          const int grow = row0 + row;
          float av;
          if (bits_in) {
            const unsigned short m16 = ((const unsigned short*)bits_s)[row * 32 + piece];
            av = (float)((m16 >> l16) & 1);
          } else {
            av = __builtin_nontemporal_load(
                adj + ((size_t)b * N_ + grow) * N_ + lcol);
          }
          const bool diag = (grow == lcol);
          if (bits_out) {
            const unsigned long long bal = __ballot(diag || av != 0.0f);
            if (l16 == 0)
              bits_out[((size_t)b * N_ + row0 + 16 * m + 4 * quad + r) * 32 + piece] =
                  (unsigned short)((bal >> (quad * 16)) & 0xFFFFull);
          }
          const float sg = sigmoidf_(acc1[m][jt][r]);
          const float v = diag ? (sg + 1e-5f) : sg * av;
          const bf16 bv = (bf16)v;
          xps[row * 520 + lcol] = bv;
          p[m][r] += (float)bv;
        }
    }
  }
#pragma unroll
  for (int m = 0; m < 4; ++m)
#pragma unroll
    for (int r = 0; r < 4; ++r) {
#pragma unroll
      for (int msk = 1; msk < 16; msk <<= 1) p[m][r] += __shfl_xor(p[m][r], msk, 64);
    }
  if (l16 == 0) {
#pragma unroll
    for (int m = 0; m < 4; ++m)
#pragma unroll
      for (int r = 0; r < 4; ++r) psum[w][16 * m + quad * 4 + r] = p[m][r];
  }
  BARSYNC();   // b2
  if (tid < 64) {
    float s = 0.0f;
#pragma unroll
    for (int ww = 0; ww < 8; ++ww) s += psum[ww][tid];
    rinvs[tid] = 1.0f / s;
  }
  BARSYNC();   // b3

  // ---- p2: normalize; attls f32 NT out (stays in flight); bf16 to xps ----
  const size_t abase = ((size_t)b * N_ + row0) * N_;
#pragma unroll
  for (int e = 0; e < 16; ++e) {
    const int idx = tid + e * 512;
    const int row = idx >> 7, c4 = (idx & 127) * 4;
    const float ri = rinvs[row];
    bf16x4 pv = *(const bf16x4*)&xps[row * 520 + c4];
    f32x4 nv;
    nv[0] = (float)pv[0] * ri; nv[1] = (float)pv[1] * ri;
    nv[2] = (float)pv[2] * ri; nv[3] = (float)pv[3] * ri;
    __builtin_nontemporal_store(nv, (f32x4*)(outA + abase + (size_t)row * N_ + c4));
    bf16x4 o;
    o[0] = (bf16)nv[0]; o[1] = (bf16)nv[1]; o[2] = (bf16)nv[2]; o[3] = (bf16)nv[3];
    *(bf16x4*)&xps[row * 520 + c4] = o;
  }
  BARSYNC();   // b4: attls stores NOT drained here (lgkm only)

  // ---- p3: x' = P @ x (B = xTpk; ks 0..11 prefetched), K = 512 -> qs ----
  {
    f32x4 acc3[4][2] = {};
#pragma unroll
    for (int ks = 0; ks < 16; ++ks) {
      bf16x8 af[4];
#pragma unroll
      for (int m = 0; m < 4; ++m)
        af[m] = *(const bf16x8*)&xps[(16 * m + l16) * 520 + ks * 32 + quad * 8];
      bf16x8 bt[2];
#pragma unroll
      for (int i = 0; i < 2; ++i)
        bt[i] = (ks < 12) ? btp[ks][i] : Xtp[UIDX((2 * w + i) * 16 + ks)];
#pragma unroll
      for (int m = 0; m < 4; ++m)
#pragma unroll
        for (int i = 0; i < 2; ++i) acc3[m][i] = MFMA16(af[m], bt[i], acc3[m][i]);
    }
    // T14: W0 fragment loads fly across b5, consumed in p4
    bf16x8 w0r[16];
#pragma unroll
    for (int j = 0; j < 16; ++j)
      w0r[j] = W08[UIDX((2 * w + (j >> 3)) * 8 + (j & 7))];
    __builtin_amdgcn_sched_barrier(0);
#pragma unroll
    for (int m = 0; m < 4; ++m)
#pragma unroll
      for (int i = 0; i < 2; ++i) {
        const int d = 32 * w + 16 * i + l16;
#pragma unroll
        for (int r = 0; r < 4; ++r)
          qs[(16 * m + quad * 4 + r) * 264 + d] = (bf16)acc3[m][i][r];
      }
    BARSYNC();   // b5: x' in qs

    // ---- p4: h = relu(x' @ W0^T + b0) -> xps (stride 264) ----
    f32x4 acc[4][2] = {};
#pragma unroll
    for (int ks = 0; ks < 8; ++ks) {
      bf16x8 af[4];
#pragma unroll
      for (int m = 0; m < 4; ++m)
        af[m] = *(const bf16x8*)&qs[(16 * m + l16) * 264 + ks * 32 + quad * 8];
#pragma unroll
      for (int m = 0; m < 4; ++m)
#pragma unroll
        for (int i = 0; i < 2; ++i)
          acc[m][i] = MFMA16(af[m], w0r[i * 8 + ks], acc[m][i]);
    }
    // T14: W1 + residual loads fly across b6, consumed in p5
    bf16x8 w1r[16];
#pragma unroll
    for (int j = 0; j < 16; ++j)
      w1r[j] = W18[UIDX((2 * w + (j >> 3)) * 8 + (j & 7))];
    bf16x8 resid[4];
#pragma unroll
    for (int j = 0; j < 4; ++j) {
      const int uu = w * 4 + j;
      resid[j] = Xbp[UIDX(((row0 >> 4) + (uu >> 3)) * 8 + (uu & 7))];
    }
    __builtin_amdgcn_sched_barrier(0);
#pragma unroll
    for (int m = 0; m < 4; ++m)
#pragma unroll
      for (int i = 0; i < 2; ++i) {
        const int col = 32 * w + 16 * i + l16;
        const float bv = b0[col];
#pragma unroll
        for (int r = 0; r < 4; ++r)
          xps[(16 * m + quad * 4 + r) * 264 + col] = (bf16)fmaxf(acc[m][i][r] + bv, 0.0f);
      }
    BARSYNC();   // b6: h in xps; qs (x') dead

    // ---- p5: x = relu(h @ W1^T + b1) + resid; emit packed outputs ----
    // stage residual strip (regs -> LDS, loads already in flight)
#pragma unroll
    for (int j = 0; j < 4; ++j) {
      const int uu = w * 4 + j;
      const int rr = uu >> 3, kc = uu & 7;
      *(bf16x8*)&qs[(rr * 16 + l16) * 264 + kc * 32 + quad * 8] = resid[j];
    }
    f32x4 acc5[4][2] = {};
#pragma unroll
    for (int ks = 0; ks < 8; ++ks) {
      bf16x8 af[4];
#pragma unroll
      for (int m = 0; m < 4; ++m)
        af[m] = *(const bf16x8*)&xps[(16 * m + l16) * 264 + ks * 32 + quad * 8];
#pragma unroll
      for (int m = 0; m < 4; ++m)
#pragma unroll
        for (int i = 0; i < 2; ++i)
          acc5[m][i] = MFMA16(af[m], w1r[i * 8 + ks], acc5[m][i]);
    }
    BARSYNC();   // b7: resid writes visible to all

#pragma unroll
    for (int m = 0; m < 4; ++m)
#pragma unroll
      for (int i = 0; i < 2; ++i) {
        const int d = 32 * w + 16 * i + l16;
        const float bv = b1[d];
#pragma unroll
        for (int r = 0; r < 4; ++r) {
          const int nl = 16 * m + quad * 4 + r;
          const float x0 = (float)qs[nl * 264 + d];
          const float t2 = fmaxf(acc5[m][i][r] + bv, 0.0f) + x0;
          qs[nl * 264 + d] = (bf16)t2;   // own cell after b7: no race
        }
      }
    BARSYNC();   // b8: output strip staged in qs [64][264]

    // packed xb_out: 32 units, dense 1KB stores
#pragma unroll
    for (int j = 0; j < 4; ++j) {
      const int uu = w * 4 + j;
      const int rr = uu >> 3, kc = uu & 7;
      const bf16x8 v = *(const bf16x8*)&qs[(rr * 16 + l16) * 264 + kc * 32 + quad * 8];
      XbpO[UIDX(((row0 >> 4) + rr) * 8 + kc)] = v;
    }
    // packed xT_out: 32 units (LDS transpose reads), dense 1KB stores
#pragma unroll
    for (int j = 0; j < 4; ++j) {
      const int uu = w * 4 + j;
      const int d16 = uu >> 1, nk = uu & 1;
      const int d = d16 * 16 + l16;
      bf16x8 v;
#pragma unroll
      for (int e = 0; e < 8; ++e)
        v[e] = qs[(nk * 32 + quad * 8 + e) * 264 + d];
      XtpO[UIDX(d16 * 16 + (row0 >> 5) + nk)] = v;
    }
  }
}

// ---------------------------------------------------------------------------
// final_proj: out = x @ Wf^T + bf (f32). A from packed xb (dense), no LDS.
// ---------------------------------------------------------------------------
__global__ __launch_bounds__(256, 4) void final_proj(
    const bf16* __restrict__ xbpk, const bf16* __restrict__ Wfp,
    const float* __restrict__ bfv, float* __restrict__ outX)
{
  const int tid = threadIdx.x, w = tid >> 6, lane = tid & 63;
  const int l16 = lane & 15, quad = lane >> 4;
  const int wg = blockIdx.x;
  const int lid = (wg & 7) * 128 + (wg >> 3);
  const int row0g = lid * 32;
  const int b = row0g >> 9, n0 = row0g & 511;
  const bf16x8* Xbp = (const bf16x8*)xbpk + (size_t)b * 16384;
  const bf16x8* Wf8 = (const bf16x8*)Wfp;
  f32x4 acc[2][4] = {};
#pragma unroll
  for (int ks = 0; ks < 8; ++ks) {
    bf16x8 af[2];
#pragma unroll
    for (int m = 0; m < 2; ++m)
      af[m] = Xbp[UIDX(((n0 >> 4) + m) * 8 + ks)];
    bf16x8 bw[4];
#pragma unroll
    for (int i = 0; i < 4; ++i)
      bw[i] = Wf8[UIDX((4 * w + i) * 8 + ks)];
#pragma unroll
    for (int m = 0; m < 2; ++m)
#pragma unroll
      for (int i = 0; i < 4; ++i) acc[m][i] = MFMA16(af[m], bw[i], acc[m][i]);
  }
#pragma unroll
  for (int m = 0; m < 2; ++m)
#pragma unroll
    for (int i = 0; i < 4; ++i) {
      const int col = 64 * w + 16 * i + l16;
      const float bv = bfv[col];
#pragma unroll
      for (int r = 0; r < 4; ++r) {
        const size_t R = (size_t)row0g + 16 * m + quad * 4 + r;
        __builtin_nontemporal_store(acc[m][i][r] + bv, outX + R * D_ + col);
      }
    }
}

extern "C" void kernel_launch(void* const* d_in, const int* in_sizes, int n_in,
                              void* d_out, int out_size, void* d_ws, size_t ws_size,
                              hipStream_t stream)
{
  const float* x_in  = (const float*)d_in[0];
  const float* adj   = (const float*)d_in[1];
  const float* wattn = (const float*)d_in[2];
  const float* battn = (const float*)d_in[3];
  const float* w0    = (const float*)d_in[4];
  const float* b0    = (const float*)d_in[5];
  const float* w1    = (const float*)d_in[6];
  const float* b1    = (const float*)d_in[7];
  const float* wf    = (const float*)d_in[8];
  const float* bfin  = (const float*)d_in[9];

  float* out_x    = (float*)d_out;                     // [B,N,D] f32
  float* out_attn = out_x + (size_t)B_ * N_ * D_;      // [L,B,N,N]

  const size_t XBN = (size_t)B_ * N_ * D_;
  const int DD2 = D_ * D_;
  bf16* wb   = (bf16*)d_ws;                            // 13*D*D packed weights
  bf16* xbp0 = wb + 13 * DD2;
  bf16* xtp0 = xbp0 + XBN;
  bf16* xbp1 = xtp0 + XBN;
  bf16* xtp1 = xbp1 + XBN;
  unsigned short* bits = (unsigned short*)(xtp1 + XBN);// [B,N,32] uint16

  // single prep launch: pack 13 weight matrices + x -> xbpk/xTpk
  prep<<<dim3(416 + 8192), 256, 0, stream>>>(
      x_in, wattn, w0, w1, wf, wb, xbp0, xtp0);

  bf16* xbps[2] = {xbp0, xbp1};
  bf16* xtps[2] = {xtp0, xtp1};
  for (int l = 0; l < L_; ++l) {
    const int pi = l & 1, po = 1 - pi;
    gat_layer<<<dim3((N_ / 64) * B_), 512, 0, stream>>>(
        xbps[pi], xtps[pi], xbps[po], xtps[po],
        wb + l * DD2, battn + l * D_,
        wb + (4 + l) * DD2, b0 + l * D_,
        wb + (8 + l) * DD2, b1 + l * D_,
        adj, (l == 0) ? nullptr : bits, (l == 0) ? bits : nullptr,
        out_attn + (size_t)l * B_ * N_ * N_);
  }
  final_proj<<<dim3((B_ * N_) / 32), 256, 0, stream>>>(
      xbps[0], wb + 12 * DD2, bfin, out_x);
}